// Round 8
// baseline (486.286 us; speedup 1.0000x reference)
//
#include <hip/hip_runtime.h>
#include <hip/hip_bf16.h>

typedef __attribute__((ext_vector_type(8))) short bvec8;   // 8 x bf16
typedef __attribute__((ext_vector_type(4))) float fvec4;   // MFMA accumulator

__device__ __forceinline__ void splitf(float f, short& hi, short& lo) {
  __hip_bfloat16 h = __float2bfloat16(f);
  float r = f - __bfloat162float(h);
  __hip_bfloat16 l = __float2bfloat16(r);
  hi = *(short*)&h;
  lo = *(short*)&l;
}
__device__ __forceinline__ float bits2f(unsigned short u) {
  unsigned int v = ((unsigned int)u) << 16;
  return __uint_as_float(v);
}

// ---------------- CSR build ----------------
__global__ void k_degree(const int* __restrict__ ei, int* __restrict__ cnt, int E, int N) {
  int i = blockIdx.x * 256 + threadIdx.x;
  if (i >= E + N) return;
  int d = (i < E) ? ei[E + i] : (i - E);   // self loops appended
  atomicAdd(&cnt[d], 1);
}

__global__ void k_scan(const int* __restrict__ cnt, int* __restrict__ off, int* __restrict__ cur, int N) {
  __shared__ int wsum[16];
  __shared__ int s_carry;
  int t = threadIdx.x, lane = t & 63, wv = t >> 6;
  if (t == 0) s_carry = 0;
  __syncthreads();
  for (int base = 0; base < N; base += 4096) {
    int idx = base + t * 4;
    int4 v = make_int4(0, 0, 0, 0);
    if (idx < N) v = *(const int4*)(cnt + idx);       // N % 4 == 0
    int s0 = v.x, s1 = s0 + v.y, s2 = s1 + v.z, s3 = s2 + v.w;
    int sc = s3;
    #pragma unroll
    for (int d = 1; d < 64; d <<= 1) {
      int u = __shfl_up(sc, d, 64);
      if (lane >= d) sc += u;
    }
    if (lane == 63) wsum[wv] = sc;
    __syncthreads();
    int carry = s_carry;
    int woff = 0;
    #pragma unroll
    for (int w = 0; w < 16; ++w) woff += (w < wv) ? wsum[w] : 0;
    int eb = carry + woff + sc - s3;                  // exclusive prefix at idx
    if (idx < N) {
      int4 o = make_int4(eb, eb + s0, eb + s1, eb + s2);
      *(int4*)(off + idx) = o;
      *(int4*)(cur + idx) = o;
    }
    __syncthreads();
    if (t == 1023) s_carry = carry + woff + sc;
    __syncthreads();
  }
  if (t == 0) off[N] = s_carry;
}

__global__ void k_scatter(const int* __restrict__ ei, int* __restrict__ cur, int* __restrict__ csr, int E, int N) {
  int i = blockIdx.x * 256 + threadIdx.x;
  if (i >= E + N) return;
  int s, d;
  if (i < E) { s = ei[i]; d = ei[E + i]; } else { s = i - E; d = i - E; }
  int p = atomicAdd(&cur[d], 1);
  csr[p] = s;
}

// ---------------- pack Wg into MFMA-fragment order (hi/lo bf16 planes) ----------------
__global__ __launch_bounds__(64) void k_wprep(const float* __restrict__ Wg, short* __restrict__ pk) {
  int tile = blockIdx.x;       // 0..31
  int lane = threadIdx.x;      // 0..63
  int w = tile >> 3, s = (tile >> 2) & 1, ct = tile & 3;
  int fq = lane >> 4, fr = lane & 15;
  bvec8 hv, lv;
  #pragma unroll
  for (int j = 0; j < 8; ++j) {
    short hh, ll;
    splitf(Wg[(size_t)(s * 32 + fq * 8 + j) * 256 + w * 64 + ct * 16 + fr], hh, ll);
    hv[j] = hh; lv[j] = ll;
  }
  *(bvec8*)(pk + tile * 1024 + lane * 8) = hv;
  *(bvec8*)(pk + tile * 1024 + 512 + lane * 8) = lv;
}

// ---------------- x0 = feat @ Wt + bt  (split-bf16 MFMA) ----------------
#define LROW 56
__global__ __launch_bounds__(256) void k_x0(const float* __restrict__ feat, const float* __restrict__ Wt,
                                            const float* __restrict__ bt, float* __restrict__ x, int N) {
  __shared__ __align__(16) short sAh[64 * LROW];
  __shared__ __align__(16) short sAl[64 * LROW];
  __shared__ __align__(16) short sBh[64 * LROW];   // [n][k] (transposed Wt tile)
  __shared__ __align__(16) short sBl[64 * LROW];

  const int t = threadIdx.x;
  const int lane = t & 63;
  const int w = t >> 6;
  const int fr = lane & 15;
  const int fq = lane >> 4;
  const int n0 = blockIdx.x * 64;

  const int ar = t >> 2;
  const int ac8 = (t & 3) * 8;
  int arow = n0 + ar; if (arow >= N) arow = N - 1;
  const float* fbase = feat + (size_t)arow * 512;
  const int bn = t & 63;
  const int bc8 = (t >> 6) * 8;

  fvec4 acc[4];
  #pragma unroll
  for (int i = 0; i < 4; ++i) acc[i] = (fvec4){0.f, 0.f, 0.f, 0.f};

  for (int s = 0; s < 16; ++s) {
    const int k0 = s * 32;
    __syncthreads();
    {
      float4 f0 = *(const float4*)(fbase + k0 + ac8);
      float4 f1 = *(const float4*)(fbase + k0 + ac8 + 4);
      float fv[8] = {f0.x, f0.y, f0.z, f0.w, f1.x, f1.y, f1.z, f1.w};
      bvec8 hv, lv;
      #pragma unroll
      for (int j = 0; j < 8; ++j) { short h, l; splitf(fv[j], h, l); hv[j] = h; lv[j] = l; }
      *(bvec8*)(sAh + ar * LROW + ac8) = hv;
      *(bvec8*)(sAl + ar * LROW + ac8) = lv;
    }
    {
      bvec8 hv, lv;
      #pragma unroll
      for (int j = 0; j < 8; ++j) {
        float v = Wt[(size_t)(k0 + bc8 + j) * 64 + bn];
        short h, l; splitf(v, h, l); hv[j] = h; lv[j] = l;
      }
      *(bvec8*)(sBh + bn * LROW + bc8) = hv;
      *(bvec8*)(sBl + bn * LROW + bc8) = lv;
    }
    __syncthreads();
    const bvec8 ah = *(const bvec8*)(sAh + (w * 16 + fr) * LROW + fq * 8);
    const bvec8 al = *(const bvec8*)(sAl + (w * 16 + fr) * LROW + fq * 8);
    #pragma unroll
    for (int nt = 0; nt < 4; ++nt) {
      const bvec8 bh = *(const bvec8*)(sBh + (nt * 16 + fr) * LROW + fq * 8);
      const bvec8 bl = *(const bvec8*)(sBl + (nt * 16 + fr) * LROW + fq * 8);
      acc[nt] = __builtin_amdgcn_mfma_f32_16x16x32_bf16(ah, bh, acc[nt], 0, 0, 0);
      acc[nt] = __builtin_amdgcn_mfma_f32_16x16x32_bf16(ah, bl, acc[nt], 0, 0, 0);
      acc[nt] = __builtin_amdgcn_mfma_f32_16x16x32_bf16(al, bh, acc[nt], 0, 0, 0);
    }
  }
  #pragma unroll
  for (int nt = 0; nt < 4; ++nt) {
    float btv = bt[nt * 16 + fr];
    #pragma unroll
    for (int r = 0; r < 4; ++r) {
      int node = n0 + w * 16 + fq * 4 + r;
      if (node < N) x[(size_t)node * 64 + nt * 16 + fr] = acc[nt][r] + btv;
    }
  }
}

// ---------------- h = x @ Wg (split-bf16 MFMA, pre-packed B) ; h bf16 ; al_s/al_d ----------------
#define HROW 72
__global__ __launch_bounds__(256) void k_h(const float* __restrict__ x, const short* __restrict__ pk,
                                           const float* __restrict__ as_, const float* __restrict__ ad_,
                                           __hip_bfloat16* __restrict__ h, float* __restrict__ als,
                                           float* __restrict__ ald, int N) {
  __shared__ __align__(16) short sAh[64 * HROW];
  __shared__ __align__(16) short sAl[64 * HROW];
  const int t = threadIdx.x;
  const int lane = t & 63;
  const int w = t >> 6;          // wave == head
  const int fr = lane & 15;
  const int fq = lane >> 4;
  const int n0 = blockIdx.x * 64;

  {
    int ar = t >> 2;
    int c0 = (t & 3) * 16;
    int arow = n0 + ar; if (arow >= N) arow = N - 1;
    const float* xb = x + (size_t)arow * 64 + c0;
    #pragma unroll
    for (int half = 0; half < 2; ++half) {
      float4 f0 = *(const float4*)(xb + half * 8);
      float4 f1 = *(const float4*)(xb + half * 8 + 4);
      float fv[8] = {f0.x, f0.y, f0.z, f0.w, f1.x, f1.y, f1.z, f1.w};
      bvec8 hv, lv;
      #pragma unroll
      for (int j = 0; j < 8; ++j) { short hh, ll; splitf(fv[j], hh, ll); hv[j] = hh; lv[j] = ll; }
      *(bvec8*)(sAh + ar * HROW + c0 + half * 8) = hv;
      *(bvec8*)(sAl + ar * HROW + c0 + half * 8) = lv;
    }
  }
  bvec8 bh[2][4], bl[2][4];
  #pragma unroll
  for (int s = 0; s < 2; ++s)
    #pragma unroll
    for (int ct = 0; ct < 4; ++ct) {
      int tile = (w * 2 + s) * 4 + ct;
      bh[s][ct] = *(const bvec8*)(pk + tile * 1024 + lane * 8);
      bl[s][ct] = *(const bvec8*)(pk + tile * 1024 + 512 + lane * 8);
    }
  __syncthreads();
  fvec4 acc[4][4];   // [nt][ct]
  #pragma unroll
  for (int nt = 0; nt < 4; ++nt)
    #pragma unroll
    for (int ct = 0; ct < 4; ++ct) acc[nt][ct] = (fvec4){0.f, 0.f, 0.f, 0.f};
  #pragma unroll
  for (int s = 0; s < 2; ++s)
    #pragma unroll
    for (int nt = 0; nt < 4; ++nt) {
      const bvec8 ah = *(const bvec8*)(sAh + (nt * 16 + fr) * HROW + s * 32 + fq * 8);
      const bvec8 al = *(const bvec8*)(sAl + (nt * 16 + fr) * HROW + s * 32 + fq * 8);
      #pragma unroll
      for (int ct = 0; ct < 4; ++ct) {
        acc[nt][ct] = __builtin_amdgcn_mfma_f32_16x16x32_bf16(ah, bh[s][ct], acc[nt][ct], 0, 0, 0);
        acc[nt][ct] = __builtin_amdgcn_mfma_f32_16x16x32_bf16(ah, bl[s][ct], acc[nt][ct], 0, 0, 0);
        acc[nt][ct] = __builtin_amdgcn_mfma_f32_16x16x32_bf16(al, bh[s][ct], acc[nt][ct], 0, 0, 0);
      }
    }
  float asv[4], adv[4];
  #pragma unroll
  for (int ct = 0; ct < 4; ++ct) {
    asv[ct] = as_[w * 64 + ct * 16 + fr];
    adv[ct] = ad_[w * 64 + ct * 16 + fr];
  }
  #pragma unroll
  for (int nt = 0; nt < 4; ++nt) {
    #pragma unroll
    for (int r = 0; r < 4; ++r) {
      int n = n0 + nt * 16 + fq * 4 + r;
      float ps = 0.f, pd = 0.f;
      #pragma unroll
      for (int ct = 0; ct < 4; ++ct) {
        ps = fmaf(acc[nt][ct][r], asv[ct], ps);
        pd = fmaf(acc[nt][ct][r], adv[ct], pd);
      }
      #pragma unroll
      for (int m = 1; m < 16; m <<= 1) { ps += __shfl_xor(ps, m, 64); pd += __shfl_xor(pd, m, 64); }
      if (fr == 0 && n < N) { als[(size_t)n * 4 + w] = ps; ald[(size_t)n * 4 + w] = pd; }
      #pragma unroll
      for (int ct = 0; ct < 4; ++ct)
        if (n < N) h[(size_t)n * 256 + w * 64 + ct * 16 + fr] = __float2bfloat16(acc[nt][ct][r]);
    }
  }
}

// ---------------- attention aggregate (4-wide, csr software-pipelined) + epilogue [+ fused final] ----------------
template <bool FINAL>
__global__ __launch_bounds__(256) void k_agg(const __hip_bfloat16* __restrict__ h, const float* __restrict__ als,
                                             const float* __restrict__ ald, const int* __restrict__ off,
                                             const int* __restrict__ csr, const float* __restrict__ bg,
                                             const float* __restrict__ gam, const float* __restrict__ bet,
                                             const float* __restrict__ pa, float* __restrict__ x,
                                             const float* __restrict__ Wp, const float* __restrict__ bp,
                                             float* __restrict__ out, int N) {
  int lane = threadIdx.x & 63;
  int n = blockIdx.x * 4 + (threadIdx.x >> 6);
  if (n >= N) return;
  int hh = lane >> 4;
  int cg = (lane & 15) * 4;
  float aldv = ald[(size_t)n * 4 + hh];
  int e0 = __builtin_amdgcn_readfirstlane(off[n]);
  int e1 = __builtin_amdgcn_readfirstlane(off[n + 1]);
  float a0 = 0, a1 = 0, a2 = 0, a3 = 0, den = 0;
  const unsigned short* hb = (const unsigned short*)h;
  const int co = hh * 64 + cg;
  int e = e0;
  int s0, s1, s2, s3;
  if (e + 4 <= e1) { s0 = csr[e]; s1 = csr[e + 1]; s2 = csr[e + 2]; s3 = csr[e + 3]; }
  while (e + 4 <= e1) {
    float q0 = als[(size_t)s0 * 4 + hh];
    float q1 = als[(size_t)s1 * 4 + hh];
    float q2 = als[(size_t)s2 * 4 + hh];
    float q3 = als[(size_t)s3 * 4 + hh];
    ushort4 g0 = *(const ushort4*)(hb + (size_t)s0 * 256 + co);
    ushort4 g1 = *(const ushort4*)(hb + (size_t)s1 * 256 + co);
    ushort4 g2 = *(const ushort4*)(hb + (size_t)s2 * 256 + co);
    ushort4 g3 = *(const ushort4*)(hb + (size_t)s3 * 256 + co);
    e += 4;
    if (e + 4 <= e1) {         // wave-uniform prefetch of next batch's indices
      s0 = csr[e]; s1 = csr[e + 1]; s2 = csr[e + 2]; s3 = csr[e + 3];
    }
    float t0 = q0 + aldv; t0 = fmaxf(t0, 0.2f * t0); float w0 = __expf(t0);
    float t1 = q1 + aldv; t1 = fmaxf(t1, 0.2f * t1); float w1 = __expf(t1);
    float t2 = q2 + aldv; t2 = fmaxf(t2, 0.2f * t2); float w2 = __expf(t2);
    float t3 = q3 + aldv; t3 = fmaxf(t3, 0.2f * t3); float w3 = __expf(t3);
    den += (w0 + w1) + (w2 + w3);
    a0 += w0 * bits2f(g0.x) + w1 * bits2f(g1.x) + w2 * bits2f(g2.x) + w3 * bits2f(g3.x);
    a1 += w0 * bits2f(g0.y) + w1 * bits2f(g1.y) + w2 * bits2f(g2.y) + w3 * bits2f(g3.y);
    a2 += w0 * bits2f(g0.z) + w1 * bits2f(g1.z) + w2 * bits2f(g2.z) + w3 * bits2f(g3.z);
    a3 += w0 * bits2f(g0.w) + w1 * bits2f(g1.w) + w2 * bits2f(g2.w) + w3 * bits2f(g3.w);
  }
  for (; e < e1; ++e) {
    int s = csr[e];
    float t = als[(size_t)s * 4 + hh] + aldv;
    t = fmaxf(t, 0.2f * t);
    float w = __expf(t);
    den += w;
    const ushort4 hv = *(const ushort4*)(hb + (size_t)s * 256 + co);
    a0 += w * bits2f(hv.x); a1 += w * bits2f(hv.y); a2 += w * bits2f(hv.z); a3 += w * bits2f(hv.w);
  }
  float inv = 1.0f / den;
  a0 *= inv; a1 *= inv; a2 *= inv; a3 *= inv;
  a0 += __shfl_xor(a0, 16, 64); a0 += __shfl_xor(a0, 32, 64);
  a1 += __shfl_xor(a1, 16, 64); a1 += __shfl_xor(a1, 32, 64);
  a2 += __shfl_xor(a2, 16, 64); a2 += __shfl_xor(a2, 32, 64);
  a3 += __shfl_xor(a3, 16, 64); a3 += __shfl_xor(a3, 32, 64);
  float v0 = a0 * 0.25f + bg[cg + 0];
  float v1 = a1 * 0.25f + bg[cg + 1];
  float v2 = a2 * 0.25f + bg[cg + 2];
  float v3 = a3 * 0.25f + bg[cg + 3];
  float sum = v0 + v1 + v2 + v3;
  #pragma unroll
  for (int m = 1; m < 16; m <<= 1) sum += __shfl_xor(sum, m, 64);
  float mu = sum * (1.f / 64.f);
  float d0 = v0 - mu, d1 = v1 - mu, d2 = v2 - mu, d3 = v3 - mu;
  float vv = d0 * d0 + d1 * d1 + d2 * d2 + d3 * d3;
  #pragma unroll
  for (int m = 1; m < 16; m <<= 1) vv += __shfl_xor(vv, m, 64);
  float rstd = rsqrtf(vv * (1.f / 64.f) + 1e-5f);
  float A = pa[0];
  float y0 = d0 * rstd * gam[cg + 0] + bet[cg + 0];
  float y1 = d1 * rstd * gam[cg + 1] + bet[cg + 1];
  float y2 = d2 * rstd * gam[cg + 2] + bet[cg + 2];
  float y3 = d3 * rstd * gam[cg + 3] + bet[cg + 3];
  y0 = y0 > 0.f ? y0 : A * y0;
  y1 = y1 > 0.f ? y1 : A * y1;
  y2 = y2 > 0.f ? y2 : A * y2;
  y3 = y3 > 0.f ? y3 : A * y3;
  // residual row (valid in lanes 0..15, 4 ch each)
  float o0 = 0.f, o1 = 0.f, o2 = 0.f, o3 = 0.f;
  if (lane < 16) {
    float4 xo = *(const float4*)(x + (size_t)n * 64 + cg);
    o0 = xo.x + y0; o1 = xo.y + y1; o2 = xo.z + y2; o3 = xo.w + y3;
  }
  if (!FINAL) {
    if (lane < 16) {
      float4 o = make_float4(o0, o1, o2, o3);
      *(float4*)(x + (size_t)n * 64 + cg) = o;   // in place: only this wave touches row n
    }
  } else {
    // z = row @ Wp + bp ; L2-normalize ; out
    float acc = bp[lane];
    #pragma unroll
    for (int g = 0; g < 16; ++g) {
      float rx = __shfl(o0, g, 64), ry = __shfl(o1, g, 64);
      float rz = __shfl(o2, g, 64), rw = __shfl(o3, g, 64);
      const float* wp = Wp + g * 4 * 64 + lane;
      acc = fmaf(rx, wp[0],   acc);
      acc = fmaf(ry, wp[64],  acc);
      acc = fmaf(rz, wp[128], acc);
      acc = fmaf(rw, wp[192], acc);
    }
    float sq = acc * acc;
    #pragma unroll
    for (int m = 1; m < 64; m <<= 1) sq += __shfl_xor(sq, m, 64);
    float nrm = fmaxf(sqrtf(sq), 1e-12f);
    out[(size_t)n * 64 + lane] = acc / nrm;
  }
}

extern "C" void kernel_launch(void* const* d_in, const int* in_sizes, int n_in,
                              void* d_out, int out_size, void* d_ws, size_t ws_size,
                              hipStream_t stream) {
  const float* feat = (const float*)d_in[0];
  const int*   ei   = (const int*)d_in[1];
  const float* Wt   = (const float*)d_in[2];
  const float* bt   = (const float*)d_in[3];
  const float* Wp   = (const float*)d_in[4];
  const float* bp   = (const float*)d_in[5];
  const float* Wg[2]  = {(const float*)d_in[6],  (const float*)d_in[13]};
  const float* as_[2] = {(const float*)d_in[7],  (const float*)d_in[14]};
  const float* ad_[2] = {(const float*)d_in[8],  (const float*)d_in[15]};
  const float* bg[2]  = {(const float*)d_in[9],  (const float*)d_in[16]};
  const float* gm[2]  = {(const float*)d_in[10], (const float*)d_in[17]};
  const float* be[2]  = {(const float*)d_in[11], (const float*)d_in[18]};
  const float* pa[2]  = {(const float*)d_in[12], (const float*)d_in[19]};

  const int N = in_sizes[0] / 512;
  const int E = in_sizes[1] / 2;

  // workspace layout
  float* x = (float*)d_ws;                                    // N*64 f32
  __hip_bfloat16* hb = (__hip_bfloat16*)(x + (size_t)N * 64); // N*256 bf16
  float* als = (float*)((short*)hb + (size_t)N * 256);        // N*4
  float* ald = als + (size_t)N * 4;                           // N*4
  int* cnt = (int*)(ald + (size_t)N * 4);                     // N
  int* cur = cnt + N;                                         // N
  int* csr = cur + N;                                         // E+N
  int* off = csr + (E + N);                                   // N+1
  short* pk0 = (short*)(((uintptr_t)(off + N + 1) + 15) & ~(uintptr_t)15);  // 32768 shorts
  short* pk1 = pk0 + 32768;

  hipMemsetAsync(cnt, 0, (size_t)N * sizeof(int), stream);
  int eb = (E + N + 255) / 256;
  k_degree<<<eb, 256, 0, stream>>>(ei, cnt, E, N);
  k_scan<<<1, 1024, 0, stream>>>(cnt, off, cur, N);
  k_scatter<<<eb, 256, 0, stream>>>(ei, cur, csr, E, N);
  k_wprep<<<32, 64, 0, stream>>>(Wg[0], pk0);
  k_wprep<<<32, 64, 0, stream>>>(Wg[1], pk1);

  int nb4 = (N + 3) / 4;
  int nb64 = (N + 63) / 64;
  k_x0<<<nb64, 256, 0, stream>>>(feat, Wt, bt, x, N);

  k_h<<<nb64, 256, 0, stream>>>(x, pk0, as_[0], ad_[0], hb, als, ald, N);
  k_agg<false><<<nb4, 256, 0, stream>>>(hb, als, ald, off, csr, bg[0], gm[0], be[0], pa[0], x,
                                        Wp, bp, (float*)d_out, N);
  k_h<<<nb64, 256, 0, stream>>>(x, pk1, as_[1], ad_[1], hb, als, ald, N);
  k_agg<true><<<nb4, 256, 0, stream>>>(hb, als, ald, off, csr, bg[1], gm[1], be[1], pa[1], x,
                                       Wp, bp, (float*)d_out, N);
}

// Round 9
// 481.805 us; speedup vs baseline: 1.0093x; 1.0093x over previous
//
#include <hip/hip_runtime.h>
#include <hip/hip_bf16.h>

typedef __attribute__((ext_vector_type(8))) short bvec8;   // 8 x bf16
typedef __attribute__((ext_vector_type(4))) float fvec4;   // MFMA accumulator

__device__ __forceinline__ void splitf(float f, short& hi, short& lo) {
  __hip_bfloat16 h = __float2bfloat16(f);
  float r = f - __bfloat162float(h);
  __hip_bfloat16 l = __float2bfloat16(r);
  hi = *(short*)&h;
  lo = *(short*)&l;
}
__device__ __forceinline__ float bits2f(unsigned short u) {
  unsigned int v = ((unsigned int)u) << 16;
  return __uint_as_float(v);
}

// ---------------- CSR build ----------------
__global__ void k_degree(const int* __restrict__ ei, int* __restrict__ cnt, int E, int N) {
  int i = blockIdx.x * 256 + threadIdx.x;
  if (i >= E + N) return;
  int d = (i < E) ? ei[E + i] : (i - E);   // self loops appended
  atomicAdd(&cnt[d], 1);
}

__global__ void k_scan(const int* __restrict__ cnt, int* __restrict__ off, int* __restrict__ cur, int N) {
  __shared__ int wsum[16];
  __shared__ int s_carry;
  int t = threadIdx.x, lane = t & 63, wv = t >> 6;
  if (t == 0) s_carry = 0;
  __syncthreads();
  for (int base = 0; base < N; base += 4096) {
    int idx = base + t * 4;
    int4 v = make_int4(0, 0, 0, 0);
    if (idx < N) v = *(const int4*)(cnt + idx);       // N % 4 == 0
    int s0 = v.x, s1 = s0 + v.y, s2 = s1 + v.z, s3 = s2 + v.w;
    int sc = s3;
    #pragma unroll
    for (int d = 1; d < 64; d <<= 1) {
      int u = __shfl_up(sc, d, 64);
      if (lane >= d) sc += u;
    }
    if (lane == 63) wsum[wv] = sc;
    __syncthreads();
    int carry = s_carry;
    int woff = 0;
    #pragma unroll
    for (int w = 0; w < 16; ++w) woff += (w < wv) ? wsum[w] : 0;
    int eb = carry + woff + sc - s3;                  // exclusive prefix at idx
    if (idx < N) {
      int4 o = make_int4(eb, eb + s0, eb + s1, eb + s2);
      *(int4*)(off + idx) = o;
      *(int4*)(cur + idx) = o;
    }
    __syncthreads();
    if (t == 1023) s_carry = carry + woff + sc;
    __syncthreads();
  }
  if (t == 0) off[N] = s_carry;
}

__global__ void k_scatter(const int* __restrict__ ei, int* __restrict__ cur, int* __restrict__ csr, int E, int N) {
  int i = blockIdx.x * 256 + threadIdx.x;
  if (i >= E + N) return;
  int s, d;
  if (i < E) { s = ei[i]; d = ei[E + i]; } else { s = i - E; d = i - E; }
  int p = atomicAdd(&cur[d], 1);
  csr[p] = s;
}

// ---------------- pack Wg into MFMA-fragment order (hi/lo bf16 planes) ----------------
__global__ __launch_bounds__(64) void k_wprep(const float* __restrict__ Wg, short* __restrict__ pk) {
  int tile = blockIdx.x;       // 0..31
  int lane = threadIdx.x;      // 0..63
  int w = tile >> 3, s = (tile >> 2) & 1, ct = tile & 3;
  int fq = lane >> 4, fr = lane & 15;
  bvec8 hv, lv;
  #pragma unroll
  for (int j = 0; j < 8; ++j) {
    short hh, ll;
    splitf(Wg[(size_t)(s * 32 + fq * 8 + j) * 256 + w * 64 + ct * 16 + fr], hh, ll);
    hv[j] = hh; lv[j] = ll;
  }
  *(bvec8*)(pk + tile * 1024 + lane * 8) = hv;
  *(bvec8*)(pk + tile * 1024 + 512 + lane * 8) = lv;
}

// ---------------- x0 = feat @ Wt + bt  (split-bf16 MFMA) ----------------
#define LROW 56
__global__ __launch_bounds__(256) void k_x0(const float* __restrict__ feat, const float* __restrict__ Wt,
                                            const float* __restrict__ bt, float* __restrict__ x, int N) {
  __shared__ __align__(16) short sAh[64 * LROW];
  __shared__ __align__(16) short sAl[64 * LROW];
  __shared__ __align__(16) short sBh[64 * LROW];   // [n][k] (transposed Wt tile)
  __shared__ __align__(16) short sBl[64 * LROW];

  const int t = threadIdx.x;
  const int lane = t & 63;
  const int w = t >> 6;
  const int fr = lane & 15;
  const int fq = lane >> 4;
  const int n0 = blockIdx.x * 64;

  const int ar = t >> 2;
  const int ac8 = (t & 3) * 8;
  int arow = n0 + ar; if (arow >= N) arow = N - 1;
  const float* fbase = feat + (size_t)arow * 512;
  const int bn = t & 63;
  const int bc8 = (t >> 6) * 8;

  fvec4 acc[4];
  #pragma unroll
  for (int i = 0; i < 4; ++i) acc[i] = (fvec4){0.f, 0.f, 0.f, 0.f};

  for (int s = 0; s < 16; ++s) {
    const int k0 = s * 32;
    __syncthreads();
    {
      float4 f0 = *(const float4*)(fbase + k0 + ac8);
      float4 f1 = *(const float4*)(fbase + k0 + ac8 + 4);
      float fv[8] = {f0.x, f0.y, f0.z, f0.w, f1.x, f1.y, f1.z, f1.w};
      bvec8 hv, lv;
      #pragma unroll
      for (int j = 0; j < 8; ++j) { short h, l; splitf(fv[j], h, l); hv[j] = h; lv[j] = l; }
      *(bvec8*)(sAh + ar * LROW + ac8) = hv;
      *(bvec8*)(sAl + ar * LROW + ac8) = lv;
    }
    {
      bvec8 hv, lv;
      #pragma unroll
      for (int j = 0; j < 8; ++j) {
        float v = Wt[(size_t)(k0 + bc8 + j) * 64 + bn];
        short h, l; splitf(v, h, l); hv[j] = h; lv[j] = l;
      }
      *(bvec8*)(sBh + bn * LROW + bc8) = hv;
      *(bvec8*)(sBl + bn * LROW + bc8) = lv;
    }
    __syncthreads();
    const bvec8 ah = *(const bvec8*)(sAh + (w * 16 + fr) * LROW + fq * 8);
    const bvec8 al = *(const bvec8*)(sAl + (w * 16 + fr) * LROW + fq * 8);
    #pragma unroll
    for (int nt = 0; nt < 4; ++nt) {
      const bvec8 bh = *(const bvec8*)(sBh + (nt * 16 + fr) * LROW + fq * 8);
      const bvec8 bl = *(const bvec8*)(sBl + (nt * 16 + fr) * LROW + fq * 8);
      acc[nt] = __builtin_amdgcn_mfma_f32_16x16x32_bf16(ah, bh, acc[nt], 0, 0, 0);
      acc[nt] = __builtin_amdgcn_mfma_f32_16x16x32_bf16(ah, bl, acc[nt], 0, 0, 0);
      acc[nt] = __builtin_amdgcn_mfma_f32_16x16x32_bf16(al, bh, acc[nt], 0, 0, 0);
    }
  }
  #pragma unroll
  for (int nt = 0; nt < 4; ++nt) {
    float btv = bt[nt * 16 + fr];
    #pragma unroll
    for (int r = 0; r < 4; ++r) {
      int node = n0 + w * 16 + fq * 4 + r;
      if (node < N) x[(size_t)node * 64 + nt * 16 + fr] = acc[nt][r] + btv;
    }
  }
}

// ---------------- h = x @ Wg (split-bf16 MFMA, pre-packed B) ; h bf16 ; al_s/al_d ----------------
#define HROW 72
__global__ __launch_bounds__(256) void k_h(const float* __restrict__ x, const short* __restrict__ pk,
                                           const float* __restrict__ as_, const float* __restrict__ ad_,
                                           __hip_bfloat16* __restrict__ h, float* __restrict__ als,
                                           float* __restrict__ ald, int N) {
  __shared__ __align__(16) short sAh[64 * HROW];
  __shared__ __align__(16) short sAl[64 * HROW];
  const int t = threadIdx.x;
  const int lane = t & 63;
  const int w = t >> 6;          // wave == head
  const int fr = lane & 15;
  const int fq = lane >> 4;
  const int n0 = blockIdx.x * 64;

  {
    int ar = t >> 2;
    int c0 = (t & 3) * 16;
    int arow = n0 + ar; if (arow >= N) arow = N - 1;
    const float* xb = x + (size_t)arow * 64 + c0;
    #pragma unroll
    for (int half = 0; half < 2; ++half) {
      float4 f0 = *(const float4*)(xb + half * 8);
      float4 f1 = *(const float4*)(xb + half * 8 + 4);
      float fv[8] = {f0.x, f0.y, f0.z, f0.w, f1.x, f1.y, f1.z, f1.w};
      bvec8 hv, lv;
      #pragma unroll
      for (int j = 0; j < 8; ++j) { short hh, ll; splitf(fv[j], hh, ll); hv[j] = hh; lv[j] = ll; }
      *(bvec8*)(sAh + ar * HROW + c0 + half * 8) = hv;
      *(bvec8*)(sAl + ar * HROW + c0 + half * 8) = lv;
    }
  }
  bvec8 bh[2][4], bl[2][4];
  #pragma unroll
  for (int s = 0; s < 2; ++s)
    #pragma unroll
    for (int ct = 0; ct < 4; ++ct) {
      int tile = (w * 2 + s) * 4 + ct;
      bh[s][ct] = *(const bvec8*)(pk + tile * 1024 + lane * 8);
      bl[s][ct] = *(const bvec8*)(pk + tile * 1024 + 512 + lane * 8);
    }
  __syncthreads();
  fvec4 acc[4][4];   // [nt][ct]
  #pragma unroll
  for (int nt = 0; nt < 4; ++nt)
    #pragma unroll
    for (int ct = 0; ct < 4; ++ct) acc[nt][ct] = (fvec4){0.f, 0.f, 0.f, 0.f};
  #pragma unroll
  for (int s = 0; s < 2; ++s)
    #pragma unroll
    for (int nt = 0; nt < 4; ++nt) {
      const bvec8 ah = *(const bvec8*)(sAh + (nt * 16 + fr) * HROW + s * 32 + fq * 8);
      const bvec8 al = *(const bvec8*)(sAl + (nt * 16 + fr) * HROW + s * 32 + fq * 8);
      #pragma unroll
      for (int ct = 0; ct < 4; ++ct) {
        acc[nt][ct] = __builtin_amdgcn_mfma_f32_16x16x32_bf16(ah, bh[s][ct], acc[nt][ct], 0, 0, 0);
        acc[nt][ct] = __builtin_amdgcn_mfma_f32_16x16x32_bf16(ah, bl[s][ct], acc[nt][ct], 0, 0, 0);
        acc[nt][ct] = __builtin_amdgcn_mfma_f32_16x16x32_bf16(al, bh[s][ct], acc[nt][ct], 0, 0, 0);
      }
    }
  float asv[4], adv[4];
  #pragma unroll
  for (int ct = 0; ct < 4; ++ct) {
    asv[ct] = as_[w * 64 + ct * 16 + fr];
    adv[ct] = ad_[w * 64 + ct * 16 + fr];
  }
  #pragma unroll
  for (int nt = 0; nt < 4; ++nt) {
    #pragma unroll
    for (int r = 0; r < 4; ++r) {
      int n = n0 + nt * 16 + fq * 4 + r;
      float ps = 0.f, pd = 0.f;
      #pragma unroll
      for (int ct = 0; ct < 4; ++ct) {
        ps = fmaf(acc[nt][ct][r], asv[ct], ps);
        pd = fmaf(acc[nt][ct][r], adv[ct], pd);
      }
      #pragma unroll
      for (int m = 1; m < 16; m <<= 1) { ps += __shfl_xor(ps, m, 64); pd += __shfl_xor(pd, m, 64); }
      if (fr == 0 && n < N) { als[(size_t)n * 4 + w] = ps; ald[(size_t)n * 4 + w] = pd; }
      #pragma unroll
      for (int ct = 0; ct < 4; ++ct)
        if (n < N) h[(size_t)n * 256 + w * 64 + ct * 16 + fr] = __float2bfloat16(acc[nt][ct][r]);
    }
  }
}

// ---------------- attention aggregate (R6 plain 4-wide loop) + epilogue [+ fused final] ----------------
template <bool FINAL>
__global__ __launch_bounds__(256) void k_agg(const __hip_bfloat16* __restrict__ h, const float* __restrict__ als,
                                             const float* __restrict__ ald, const int* __restrict__ off,
                                             const int* __restrict__ csr, const float* __restrict__ bg,
                                             const float* __restrict__ gam, const float* __restrict__ bet,
                                             const float* __restrict__ pa, float* __restrict__ x,
                                             const float* __restrict__ Wp, const float* __restrict__ bp,
                                             float* __restrict__ out, int N) {
  int lane = threadIdx.x & 63;
  int n = blockIdx.x * 4 + (threadIdx.x >> 6);
  if (n >= N) return;
  int hh = lane >> 4;
  int cg = (lane & 15) * 4;
  float aldv = ald[(size_t)n * 4 + hh];
  int e0 = __builtin_amdgcn_readfirstlane(off[n]);
  int e1 = __builtin_amdgcn_readfirstlane(off[n + 1]);
  float a0 = 0, a1 = 0, a2 = 0, a3 = 0, den = 0;
  const unsigned short* hb = (const unsigned short*)h;
  const int co = hh * 64 + cg;
  int e = e0;
  for (; e + 4 <= e1; e += 4) {
    int s0 = csr[e + 0], s1 = csr[e + 1], s2 = csr[e + 2], s3 = csr[e + 3];
    float q0 = als[(size_t)s0 * 4 + hh];
    float q1 = als[(size_t)s1 * 4 + hh];
    float q2 = als[(size_t)s2 * 4 + hh];
    float q3 = als[(size_t)s3 * 4 + hh];
    ushort4 g0 = *(const ushort4*)(hb + (size_t)s0 * 256 + co);
    ushort4 g1 = *(const ushort4*)(hb + (size_t)s1 * 256 + co);
    ushort4 g2 = *(const ushort4*)(hb + (size_t)s2 * 256 + co);
    ushort4 g3 = *(const ushort4*)(hb + (size_t)s3 * 256 + co);
    float t0 = q0 + aldv; t0 = fmaxf(t0, 0.2f * t0); float w0 = __expf(t0);
    float t1 = q1 + aldv; t1 = fmaxf(t1, 0.2f * t1); float w1 = __expf(t1);
    float t2 = q2 + aldv; t2 = fmaxf(t2, 0.2f * t2); float w2 = __expf(t2);
    float t3 = q3 + aldv; t3 = fmaxf(t3, 0.2f * t3); float w3 = __expf(t3);
    den += (w0 + w1) + (w2 + w3);
    a0 += w0 * bits2f(g0.x) + w1 * bits2f(g1.x) + w2 * bits2f(g2.x) + w3 * bits2f(g3.x);
    a1 += w0 * bits2f(g0.y) + w1 * bits2f(g1.y) + w2 * bits2f(g2.y) + w3 * bits2f(g3.y);
    a2 += w0 * bits2f(g0.z) + w1 * bits2f(g1.z) + w2 * bits2f(g2.z) + w3 * bits2f(g3.z);
    a3 += w0 * bits2f(g0.w) + w1 * bits2f(g1.w) + w2 * bits2f(g2.w) + w3 * bits2f(g3.w);
  }
  for (; e < e1; ++e) {
    int s = csr[e];
    float t = als[(size_t)s * 4 + hh] + aldv;
    t = fmaxf(t, 0.2f * t);
    float w = __expf(t);
    den += w;
    const ushort4 hv = *(const ushort4*)(hb + (size_t)s * 256 + co);
    a0 += w * bits2f(hv.x); a1 += w * bits2f(hv.y); a2 += w * bits2f(hv.z); a3 += w * bits2f(hv.w);
  }
  float inv = 1.0f / den;
  a0 *= inv; a1 *= inv; a2 *= inv; a3 *= inv;
  a0 += __shfl_xor(a0, 16, 64); a0 += __shfl_xor(a0, 32, 64);
  a1 += __shfl_xor(a1, 16, 64); a1 += __shfl_xor(a1, 32, 64);
  a2 += __shfl_xor(a2, 16, 64); a2 += __shfl_xor(a2, 32, 64);
  a3 += __shfl_xor(a3, 16, 64); a3 += __shfl_xor(a3, 32, 64);
  float v0 = a0 * 0.25f + bg[cg + 0];
  float v1 = a1 * 0.25f + bg[cg + 1];
  float v2 = a2 * 0.25f + bg[cg + 2];
  float v3 = a3 * 0.25f + bg[cg + 3];
  float sum = v0 + v1 + v2 + v3;
  #pragma unroll
  for (int m = 1; m < 16; m <<= 1) sum += __shfl_xor(sum, m, 64);
  float mu = sum * (1.f / 64.f);
  float d0 = v0 - mu, d1 = v1 - mu, d2 = v2 - mu, d3 = v3 - mu;
  float vv = d0 * d0 + d1 * d1 + d2 * d2 + d3 * d3;
  #pragma unroll
  for (int m = 1; m < 16; m <<= 1) vv += __shfl_xor(vv, m, 64);
  float rstd = rsqrtf(vv * (1.f / 64.f) + 1e-5f);
  float A = pa[0];
  float y0 = d0 * rstd * gam[cg + 0] + bet[cg + 0];
  float y1 = d1 * rstd * gam[cg + 1] + bet[cg + 1];
  float y2 = d2 * rstd * gam[cg + 2] + bet[cg + 2];
  float y3 = d3 * rstd * gam[cg + 3] + bet[cg + 3];
  y0 = y0 > 0.f ? y0 : A * y0;
  y1 = y1 > 0.f ? y1 : A * y1;
  y2 = y2 > 0.f ? y2 : A * y2;
  y3 = y3 > 0.f ? y3 : A * y3;
  // residual row (valid in lanes 0..15, 4 ch each)
  float o0 = 0.f, o1 = 0.f, o2 = 0.f, o3 = 0.f;
  if (lane < 16) {
    float4 xo = *(const float4*)(x + (size_t)n * 64 + cg);
    o0 = xo.x + y0; o1 = xo.y + y1; o2 = xo.z + y2; o3 = xo.w + y3;
  }
  if (!FINAL) {
    if (lane < 16) {
      float4 o = make_float4(o0, o1, o2, o3);
      *(float4*)(x + (size_t)n * 64 + cg) = o;   // in place: only this wave touches row n
    }
  } else {
    // z = row @ Wp + bp ; L2-normalize ; out
    float acc = bp[lane];
    #pragma unroll
    for (int g = 0; g < 16; ++g) {
      float rx = __shfl(o0, g, 64), ry = __shfl(o1, g, 64);
      float rz = __shfl(o2, g, 64), rw = __shfl(o3, g, 64);
      const float* wp = Wp + g * 4 * 64 + lane;
      acc = fmaf(rx, wp[0],   acc);
      acc = fmaf(ry, wp[64],  acc);
      acc = fmaf(rz, wp[128], acc);
      acc = fmaf(rw, wp[192], acc);
    }
    float sq = acc * acc;
    #pragma unroll
    for (int m = 1; m < 64; m <<= 1) sq += __shfl_xor(sq, m, 64);
    float nrm = fmaxf(sqrtf(sq), 1e-12f);
    out[(size_t)n * 64 + lane] = acc / nrm;
  }
}

extern "C" void kernel_launch(void* const* d_in, const int* in_sizes, int n_in,
                              void* d_out, int out_size, void* d_ws, size_t ws_size,
                              hipStream_t stream) {
  const float* feat = (const float*)d_in[0];
  const int*   ei   = (const int*)d_in[1];
  const float* Wt   = (const float*)d_in[2];
  const float* bt   = (const float*)d_in[3];
  const float* Wp   = (const float*)d_in[4];
  const float* bp   = (const float*)d_in[5];
  const float* Wg[2]  = {(const float*)d_in[6],  (const float*)d_in[13]};
  const float* as_[2] = {(const float*)d_in[7],  (const float*)d_in[14]};
  const float* ad_[2] = {(const float*)d_in[8],  (const float*)d_in[15]};
  const float* bg[2]  = {(const float*)d_in[9],  (const float*)d_in[16]};
  const float* gm[2]  = {(const float*)d_in[10], (const float*)d_in[17]};
  const float* be[2]  = {(const float*)d_in[11], (const float*)d_in[18]};
  const float* pa[2]  = {(const float*)d_in[12], (const float*)d_in[19]};

  const int N = in_sizes[0] / 512;
  const int E = in_sizes[1] / 2;

  // workspace layout
  float* x = (float*)d_ws;                                    // N*64 f32
  __hip_bfloat16* hb = (__hip_bfloat16*)(x + (size_t)N * 64); // N*256 bf16
  float* als = (float*)((short*)hb + (size_t)N * 256);        // N*4
  float* ald = als + (size_t)N * 4;                           // N*4
  int* cnt = (int*)(ald + (size_t)N * 4);                     // N
  int* cur = cnt + N;                                         // N
  int* csr = cur + N;                                         // E+N
  int* off = csr + (E + N);                                   // N+1
  short* pk0 = (short*)(((uintptr_t)(off + N + 1) + 15) & ~(uintptr_t)15);  // 32768 shorts
  short* pk1 = pk0 + 32768;

  hipMemsetAsync(cnt, 0, (size_t)N * sizeof(int), stream);
  int eb = (E + N + 255) / 256;
  k_degree<<<eb, 256, 0, stream>>>(ei, cnt, E, N);
  k_scan<<<1, 1024, 0, stream>>>(cnt, off, cur, N);
  k_scatter<<<eb, 256, 0, stream>>>(ei, cur, csr, E, N);
  k_wprep<<<32, 64, 0, stream>>>(Wg[0], pk0);
  k_wprep<<<32, 64, 0, stream>>>(Wg[1], pk1);

  int nb4 = (N + 3) / 4;
  int nb64 = (N + 63) / 64;
  k_x0<<<nb64, 256, 0, stream>>>(feat, Wt, bt, x, N);

  k_h<<<nb64, 256, 0, stream>>>(x, pk0, as_[0], ad_[0], hb, als, ald, N);
  k_agg<false><<<nb4, 256, 0, stream>>>(hb, als, ald, off, csr, bg[0], gm[0], be[0], pa[0], x,
                                        Wp, bp, (float*)d_out, N);
  k_h<<<nb64, 256, 0, stream>>>(x, pk1, as_[1], ad_[1], hb, als, ald, N);
  k_agg<true><<<nb4, 256, 0, stream>>>(hb, als, ald, off, csr, bg[1], gm[1], be[1], pa[1], x,
                                       Wp, bp, (float*)d_out, N);
}